// Round 3
// baseline (389.834 us; speedup 1.0000x reference)
//
#include <hip/hip_runtime.h>

#define N_NODES 50000
#define N_EDGES 800000
// IN=HID=64, OUT=16, N_RELS=16, N_BASES=4 (hard-coded below)

// ===========================================================================
// CSR build: histogram -> hierarchical exclusive scan -> cursor scatter.
// ===========================================================================
__global__ __launch_bounds__(256) void k_hist(const int* __restrict__ dst,
                                              int* __restrict__ deg) {
  int e = blockIdx.x * 256 + threadIdx.x;
  if (e < N_EDGES) atomicAdd(&deg[dst[e]], 1);
}

// Block-level inclusive scan of 1024 elems; writes local inclusive to rowp[i+1]
// and the block total to bsum[blockIdx].
__global__ __launch_bounds__(1024) void k_scan1(const int* __restrict__ deg,
                                                int* __restrict__ rowp,
                                                int* __restrict__ bsum) {
  __shared__ int wsum[16];
  const int tid = threadIdx.x, lane = tid & 63, wid = tid >> 6;
  const int i = blockIdx.x * 1024 + tid;
  int v = (i < N_NODES) ? deg[i] : 0;
  int incl = v;
#pragma unroll
  for (int off = 1; off < 64; off <<= 1) {
    int t = __shfl_up(incl, off, 64);
    if (lane >= off) incl += t;
  }
  if (lane == 63) wsum[wid] = incl;
  __syncthreads();
  if (tid < 16) {
    int wi = wsum[tid];
#pragma unroll
    for (int off = 1; off < 16; off <<= 1) {
      int t = __shfl_up(wi, off, 64);
      if (lane >= off) wi += t;
    }
    wsum[tid] = wi;
  }
  __syncthreads();
  int woff = (wid > 0) ? wsum[wid - 1] : 0;
  int incl_all = incl + woff;
  if (i < N_NODES) rowp[i + 1] = incl_all;
  if (tid == 1023) bsum[blockIdx.x] = incl_all;
}

// Scan the 49 block sums -> exclusive offsets.
__global__ __launch_bounds__(64) void k_scan2(const int* __restrict__ bsum,
                                              int* __restrict__ boff,
                                              int nblk) {
  const int lane = threadIdx.x;
  int v = (lane < nblk) ? bsum[lane] : 0;
  int incl = v;
#pragma unroll
  for (int off = 1; off < 64; off <<= 1) {
    int t = __shfl_up(incl, off, 64);
    if (lane >= off) incl += t;
  }
  if (lane < nblk) boff[lane] = incl - v;
}

__global__ __launch_bounds__(1024) void k_scan3(int* __restrict__ rowp,
                                                const int* __restrict__ boff) {
  const int i = blockIdx.x * 1024 + threadIdx.x;
  if (i < N_NODES) rowp[i + 1] += boff[blockIdx.x];
  if (i == 0) rowp[0] = 0;
}

__global__ __launch_bounds__(256) void k_scatter(
    const int* __restrict__ src, const int* __restrict__ dst,
    const int* __restrict__ ety, const float* __restrict__ enorm,
    const int* __restrict__ rowp, int* __restrict__ cursor,
    int2* __restrict__ s_edge) {
  int e = blockIdx.x * 256 + threadIdx.x;
  if (e >= N_EDGES) return;
  int d = dst[e];
  int pos = rowp[d] + atomicAdd(&cursor[d], 1);
  s_edge[pos] = make_int2(src[e] | (ety[e] << 16), __float_as_int(enorm[e]));
}

// ===========================================================================
// Layer-1 gather: u[d, b, k] = sum_{e->d} norm_e * coef1[t_e, b] * x[src_e, k]
// One wave per node; eslot = lane>>4 (4 edges in flight), ch = lane&15
// (float4 over 64 channels). 1-ahead software pipeline on (rec, feat).
// ===========================================================================
__global__ __launch_bounds__(256) void k_gather1(
    const int* __restrict__ rowp, const int2* __restrict__ s_edge,
    const float4* __restrict__ xv,     // [N][16] float4
    const float4* __restrict__ coefv,  // [16]
    float4* __restrict__ uv) {         // [N][4][16] float4
  const int node = blockIdx.x * 4 + (threadIdx.x >> 6);
  const int lane = threadIdx.x & 63;
  const int eslot = lane >> 4, ch = lane & 15;
  const int beg = rowp[node], end = rowp[node + 1];
  float4 a0 = {0, 0, 0, 0}, a1 = {0, 0, 0, 0}, a2 = {0, 0, 0, 0}, a3 = {0, 0, 0, 0};
  int j = beg + eslot;
  int2 rec = make_int2(0, 0);
  float4 f = {0, 0, 0, 0};
  if (j < end) {
    rec = s_edge[j];
    f = xv[(rec.x & 0xFFFF) * 16 + ch];
  }
  while (j < end) {
    const int jn = j + 4;
    int2 rec_n = make_int2(0, 0);
    float4 f_n = {0, 0, 0, 0};
    if (jn < end) {
      rec_n = s_edge[jn];
      f_n = xv[(rec_n.x & 0xFFFF) * 16 + ch];
    }
    const float nm = __int_as_float(rec.y);
    const float4 c = coefv[(rec.x >> 16) & 15];
    const float w0 = nm * c.x, w1 = nm * c.y, w2 = nm * c.z, w3 = nm * c.w;
    a0.x += w0 * f.x; a0.y += w0 * f.y; a0.z += w0 * f.z; a0.w += w0 * f.w;
    a1.x += w1 * f.x; a1.y += w1 * f.y; a1.z += w1 * f.z; a1.w += w1 * f.w;
    a2.x += w2 * f.x; a2.y += w2 * f.y; a2.z += w2 * f.z; a2.w += w2 * f.w;
    a3.x += w3 * f.x; a3.y += w3 * f.y; a3.z += w3 * f.z; a3.w += w3 * f.w;
    j = jn; rec = rec_n; f = f_n;
  }
#define RED1(x) x += __shfl_down(x, 32, 64); x += __shfl_down(x, 16, 64)
  RED1(a0.x); RED1(a0.y); RED1(a0.z); RED1(a0.w);
  RED1(a1.x); RED1(a1.y); RED1(a1.z); RED1(a1.w);
  RED1(a2.x); RED1(a2.y); RED1(a2.z); RED1(a2.w);
  RED1(a3.x); RED1(a3.y); RED1(a3.z); RED1(a3.w);
#undef RED1
  if (eslot == 0) {
    float4* up = uv + (size_t)node * 64;
    up[ch] = a0; up[16 + ch] = a1; up[32 + ch] = a2; up[48 + ch] = a3;
  }
}

// ===========================================================================
// GEMM1: h1[n][o] = relu(sum_q u[n][q]*B1[q][o] + bias1[o]), q=256, o=64.
// Thread = (node, og): n = gtid>>4, og = gtid&15 (one float4 of outputs).
// Grid 3125 blocks -> 12.5k waves (full occupancy); unroll 4 for MLP.
// ===========================================================================
__global__ __launch_bounds__(256) void k_gemm1(
    const float4* __restrict__ uv,     // [N][64] float4 (flat q = 4*m + comp)
    const float4* __restrict__ bv,     // bases1 flat [256][16] float4
    const float4* __restrict__ biasv,  // [16]
    float4* __restrict__ hv) {         // h1 [N][16] float4
  const int gt = blockIdx.x * 256 + threadIdx.x;  // 0..800000
  const int n = gt >> 4, og = gt & 15;
  float4 acc = {0, 0, 0, 0};
#pragma unroll 4
  for (int qb = 0; qb < 64; ++qb) {
    const float4 u = uv[(size_t)n * 64 + qb];
    const float4 b0 = bv[(qb * 4 + 0) * 16 + og];
    const float4 b1 = bv[(qb * 4 + 1) * 16 + og];
    const float4 b2 = bv[(qb * 4 + 2) * 16 + og];
    const float4 b3 = bv[(qb * 4 + 3) * 16 + og];
    acc.x += u.x * b0.x + u.y * b1.x + u.z * b2.x + u.w * b3.x;
    acc.y += u.x * b0.y + u.y * b1.y + u.z * b2.y + u.w * b3.y;
    acc.z += u.x * b0.z + u.y * b1.z + u.z * b2.z + u.w * b3.z;
    acc.w += u.x * b0.w + u.y * b1.w + u.z * b2.w + u.w * b3.w;
  }
  const float4 bs = biasv[og];
  float4 r;
  r.x = fmaxf(acc.x + bs.x, 0.f);
  r.y = fmaxf(acc.y + bs.y, 0.f);
  r.z = fmaxf(acc.z + bs.z, 0.f);
  r.w = fmaxf(acc.w + bs.w, 0.f);
  hv[(size_t)n * 16 + og] = r;
}

// ===========================================================================
// Layer-2 pre-transform: Y2[n][o][b] = sum_k h1[n][k] * bases2[b][k][o].
// Thread = (node, o): o = gtid&15. acc float4 runs over the 4 bases.
// ===========================================================================
__global__ __launch_bounds__(256) void k_gemmY2(
    const float4* __restrict__ h1v,  // [N][16] float4
    const float* __restrict__ b2,    // bases2 [4][64][16]
    float4* __restrict__ y2v) {      // [N][16] float4 (o-major, b inner)
  const int gt = blockIdx.x * 256 + threadIdx.x;
  const int n = gt >> 4, o = gt & 15;
  float4 acc = {0, 0, 0, 0};
#pragma unroll 4
  for (int kb = 0; kb < 16; ++kb) {
    const float4 h4 = h1v[(size_t)n * 16 + kb];
#pragma unroll
    for (int r = 0; r < 4; ++r) {
      const int k = kb * 4 + r;
      const float hval = (r == 0) ? h4.x : (r == 1) ? h4.y : (r == 2) ? h4.z : h4.w;
      acc.x += hval * b2[0 * 1024 + k * 16 + o];
      acc.y += hval * b2[1 * 1024 + k * 16 + o];
      acc.z += hval * b2[2 * 1024 + k * 16 + o];
      acc.w += hval * b2[3 * 1024 + k * 16 + o];
    }
  }
  y2v[(size_t)n * 16 + o] = acc;
}

// ===========================================================================
// Layer-2 gather (final): out[d][o] = relu(bias2[o] +
//   sum_{e->d} norm_e * dot(coef2[t_e], Y2[src_e][o][:]))
// One wave per node; eslot = lane>>4, o = lane&15; scalar acc per lane.
// ===========================================================================
__global__ __launch_bounds__(256) void k_gather2(
    const int* __restrict__ rowp, const int2* __restrict__ s_edge,
    const float4* __restrict__ y2v,    // [N][16] float4
    const float4* __restrict__ coefv,  // [16]
    const float* __restrict__ bias2,   // [16]
    float* __restrict__ out) {         // [N][16]
  const int node = blockIdx.x * 4 + (threadIdx.x >> 6);
  const int lane = threadIdx.x & 63;
  const int eslot = lane >> 4, o = lane & 15;
  const int beg = rowp[node], end = rowp[node + 1];
  float acc = 0.f;
  int j = beg + eslot;
  int2 rec = make_int2(0, 0);
  float4 y = {0, 0, 0, 0};
  if (j < end) {
    rec = s_edge[j];
    y = y2v[(rec.x & 0xFFFF) * 16 + o];
  }
  while (j < end) {
    const int jn = j + 4;
    int2 rec_n = make_int2(0, 0);
    float4 y_n = {0, 0, 0, 0};
    if (jn < end) {
      rec_n = s_edge[jn];
      y_n = y2v[(rec_n.x & 0xFFFF) * 16 + o];
    }
    const float nm = __int_as_float(rec.y);
    const float4 c = coefv[(rec.x >> 16) & 15];
    acc += nm * (c.x * y.x + c.y * y.y + c.z * y.z + c.w * y.w);
    j = jn; rec = rec_n; y = y_n;
  }
  acc += __shfl_down(acc, 32, 64);
  acc += __shfl_down(acc, 16, 64);
  if (eslot == 0) out[(size_t)node * 16 + o] = fmaxf(acc + bias2[o], 0.f);
}

extern "C" void kernel_launch(void* const* d_in, const int* in_sizes, int n_in,
                              void* d_out, int out_size, void* d_ws, size_t ws_size,
                              hipStream_t stream) {
  const float* feats  = (const float*)d_in[0];
  const int*   src    = (const int*)d_in[1];
  const int*   dst    = (const int*)d_in[2];
  const int*   etype  = (const int*)d_in[3];
  const float* enorm  = (const float*)d_in[4];
  const float* bases1 = (const float*)d_in[5];
  const float* coef1  = (const float*)d_in[6];
  const float* bias1  = (const float*)d_in[7];
  const float* bases2 = (const float*)d_in[8];
  const float* coef2  = (const float*)d_in[9];
  const float* bias2  = (const float*)d_in[10];

  // Workspace: u (51.2 MB, reused as Y2) | h1 (12.8 MB) | s_edge (6.4 MB)
  //            | deg | cursor | rowp | bsum | boff
  float* u12    = (float*)d_ws;                       // N*256 floats
  float* h1     = u12 + (size_t)N_NODES * 256;        // N*64 floats
  int2*  s_edge = (int2*)(h1 + (size_t)N_NODES * 64); // N_EDGES int2 (8B-aligned)
  int*   deg    = (int*)(s_edge + N_EDGES);           // N
  int*   cursor = deg + N_NODES;                      // N (adjacent: one memset)
  int*   rowp   = cursor + N_NODES;                   // N+1
  int*   bsum   = rowp + N_NODES + 1;                 // 64
  int*   boff   = bsum + 64;                          // 64

  const int SCAN_BLKS = (N_NODES + 1023) / 1024;  // 49

  hipMemsetAsync(deg, 0, 2 * N_NODES * sizeof(int), stream);  // deg + cursor

  k_hist<<<N_EDGES / 256, 256, 0, stream>>>(dst, deg);
  k_scan1<<<SCAN_BLKS, 1024, 0, stream>>>(deg, rowp, bsum);
  k_scan2<<<1, 64, 0, stream>>>(bsum, boff, SCAN_BLKS);
  k_scan3<<<SCAN_BLKS, 1024, 0, stream>>>(rowp, boff);
  k_scatter<<<N_EDGES / 256, 256, 0, stream>>>(src, dst, etype, enorm,
                                               rowp, cursor, s_edge);
  // Layer 1: gather feats -> u, then u @ bases1 (+bias, relu) -> h1
  k_gather1<<<N_NODES / 4, 256, 0, stream>>>(rowp, s_edge, (const float4*)feats,
                                             (const float4*)coef1, (float4*)u12);
  k_gemm1<<<(N_NODES * 16) / 256, 256, 0, stream>>>(
      (const float4*)u12, (const float4*)bases1, (const float4*)bias1,
      (float4*)h1);
  // Layer 2: pre-transform h1 -> Y2 (in u12), gather Y2 -> out (+bias, relu)
  k_gemmY2<<<(N_NODES * 16) / 256, 256, 0, stream>>>(
      (const float4*)h1, bases2, (float4*)u12);
  k_gather2<<<N_NODES / 4, 256, 0, stream>>>(rowp, s_edge, (const float4*)u12,
                                             (const float4*)coef2, bias2,
                                             (float*)d_out);
}

// Round 4
// 322.454 us; speedup vs baseline: 1.2090x; 1.2090x over previous
//
#include <hip/hip_runtime.h>

#define N_NODES 50000
#define N_EDGES 800000
// IN=HID=64, OUT=16, N_RELS=16, N_BASES=4 (hard-coded below)

// ===========================================================================
// Histogram of dst + per-edge rank (return value of the atomic).
// rank write is coalesced; the atomic order within a dst is arbitrary, which
// only permutes the fp32 summation order (within tolerance).
// ===========================================================================
__global__ __launch_bounds__(256) void k_hist(const int* __restrict__ dst,
                                              int* __restrict__ deg,
                                              int* __restrict__ rank) {
  int e = blockIdx.x * 256 + threadIdx.x;
  if (e < N_EDGES) rank[e] = atomicAdd(&deg[dst[e]], 1);
}

// Block-level inclusive scan of 1024 elems -> rowp[i+1]; block total -> bsum.
__global__ __launch_bounds__(1024) void k_scan1(const int* __restrict__ deg,
                                                int* __restrict__ rowp,
                                                int* __restrict__ bsum) {
  __shared__ int wsum[16];
  const int tid = threadIdx.x, lane = tid & 63, wid = tid >> 6;
  const int i = blockIdx.x * 1024 + tid;
  int v = (i < N_NODES) ? deg[i] : 0;
  int incl = v;
#pragma unroll
  for (int off = 1; off < 64; off <<= 1) {
    int t = __shfl_up(incl, off, 64);
    if (lane >= off) incl += t;
  }
  if (lane == 63) wsum[wid] = incl;
  __syncthreads();
  if (tid < 16) {
    int wi = wsum[tid];
#pragma unroll
    for (int off = 1; off < 16; off <<= 1) {
      int t = __shfl_up(wi, off, 64);
      if (lane >= off) wi += t;
    }
    wsum[tid] = wi;
  }
  __syncthreads();
  int woff = (wid > 0) ? wsum[wid - 1] : 0;
  int incl_all = incl + woff;
  if (i < N_NODES) rowp[i + 1] = incl_all;
  if (tid == 1023) bsum[blockIdx.x] = incl_all;
}

__global__ __launch_bounds__(64) void k_scan2(const int* __restrict__ bsum,
                                              int* __restrict__ boff,
                                              int nblk) {
  const int lane = threadIdx.x;
  int v = (lane < nblk) ? bsum[lane] : 0;
  int incl = v;
#pragma unroll
  for (int off = 1; off < 64; off <<= 1) {
    int t = __shfl_up(incl, off, 64);
    if (lane >= off) incl += t;
  }
  if (lane < nblk) boff[lane] = incl - v;
}

__global__ __launch_bounds__(1024) void k_scan3(int* __restrict__ rowp,
                                                const int* __restrict__ boff) {
  const int i = blockIdx.x * 1024 + threadIdx.x;
  if (i < N_NODES) rowp[i + 1] += boff[blockIdx.x];
  if (i == 0) rowp[0] = 0;
}

// Atomic-free scatter into dst-sorted order using precomputed ranks.
__global__ __launch_bounds__(256) void k_scatter(
    const int* __restrict__ src, const int* __restrict__ dst,
    const int* __restrict__ ety, const float* __restrict__ enorm,
    const int* __restrict__ rowp, const int* __restrict__ rank,
    int2* __restrict__ s_edge) {
  int e = blockIdx.x * 256 + threadIdx.x;
  if (e >= N_EDGES) return;
  int pos = rowp[dst[e]] + rank[e];
  s_edge[pos] = make_int2(src[e] | (ety[e] << 16), __float_as_int(enorm[e]));
}

// ===========================================================================
// Fused layer 1: per block, 4 nodes (one wave each).
// Phase A (gather): u[d, b, k] = sum_{e->d} norm_e*coef1[t_e,b]*x[src_e,k]
//   eslot = lane>>4 (4 edges in flight, 1-ahead prefetch), ch = lane&15
//   (float4 over 64 channels). shfl-reduce over eslots -> LDS u[4][256].
// Phase B (gemm): thread = (node = tid>>6, o = tid&63):
//   h1[n][o] = relu(sum_q u[n][q]*bases1[q][o] + bias1[o]);  q = 4*qb+r.
//   LDS reads are wave-uniform broadcasts; bases1 reads 256B coalesced.
// Kills the 51 MB u round-trip through L3 entirely.
// ===========================================================================
__global__ __launch_bounds__(256) void k_l1_fused(
    const int* __restrict__ rowp, const int2* __restrict__ s_edge,
    const float4* __restrict__ xv,     // feats [N][16] float4
    const float4* __restrict__ coefv,  // coef1 [16]
    const float* __restrict__ bases1,  // [256][64] flat (q = b*64+k major)
    const float* __restrict__ bias1,   // [64]
    float* __restrict__ h1) {          // [N][64]
  __shared__ float4 lds_u[4][64];  // [node][q/4] -> 4 KB
  const int wid = threadIdx.x >> 6;
  const int lane = threadIdx.x & 63;
  const int node = blockIdx.x * 4 + wid;
  const int eslot = lane >> 4, ch = lane & 15;
  const int beg = rowp[node], end = rowp[node + 1];
  float4 a0 = {0, 0, 0, 0}, a1 = {0, 0, 0, 0}, a2 = {0, 0, 0, 0}, a3 = {0, 0, 0, 0};
  int j = beg + eslot;
  int2 rec = make_int2(0, 0);
  float4 f = {0, 0, 0, 0};
  if (j < end) {
    rec = s_edge[j];
    f = xv[(rec.x & 0xFFFF) * 16 + ch];
  }
  while (j < end) {
    const int jn = j + 4;
    int2 rec_n = make_int2(0, 0);
    float4 f_n = {0, 0, 0, 0};
    if (jn < end) {
      rec_n = s_edge[jn];
      f_n = xv[(rec_n.x & 0xFFFF) * 16 + ch];
    }
    const float nm = __int_as_float(rec.y);
    const float4 c = coefv[(rec.x >> 16) & 15];
    const float w0 = nm * c.x, w1 = nm * c.y, w2 = nm * c.z, w3 = nm * c.w;
    a0.x += w0 * f.x; a0.y += w0 * f.y; a0.z += w0 * f.z; a0.w += w0 * f.w;
    a1.x += w1 * f.x; a1.y += w1 * f.y; a1.z += w1 * f.z; a1.w += w1 * f.w;
    a2.x += w2 * f.x; a2.y += w2 * f.y; a2.z += w2 * f.z; a2.w += w2 * f.w;
    a3.x += w3 * f.x; a3.y += w3 * f.y; a3.z += w3 * f.z; a3.w += w3 * f.w;
    j = jn; rec = rec_n; f = f_n;
  }
#define RED1(x) x += __shfl_down(x, 32, 64); x += __shfl_down(x, 16, 64)
  RED1(a0.x); RED1(a0.y); RED1(a0.z); RED1(a0.w);
  RED1(a1.x); RED1(a1.y); RED1(a1.z); RED1(a1.w);
  RED1(a2.x); RED1(a2.y); RED1(a2.z); RED1(a2.w);
  RED1(a3.x); RED1(a3.y); RED1(a3.z); RED1(a3.w);
#undef RED1
  // lane ch holds u[b][4ch..4ch+3]; flat float4 index = b*16+ch <=> q = 4*idx+r
  if (eslot == 0) {
    lds_u[wid][ch] = a0;
    lds_u[wid][16 + ch] = a1;
    lds_u[wid][32 + ch] = a2;
    lds_u[wid][48 + ch] = a3;
  }
  __syncthreads();
  // Phase B
  const int o = lane;  // 0..63, node = wid
  float acc = 0.f;
#pragma unroll 4
  for (int qb = 0; qb < 64; ++qb) {
    const float4 uq = lds_u[wid][qb];  // wave-uniform broadcast
    acc += uq.x * bases1[(4 * qb + 0) * 64 + o];
    acc += uq.y * bases1[(4 * qb + 1) * 64 + o];
    acc += uq.z * bases1[(4 * qb + 2) * 64 + o];
    acc += uq.w * bases1[(4 * qb + 3) * 64 + o];
  }
  h1[(size_t)node * 64 + o] = fmaxf(acc + bias1[o], 0.f);
}

// ===========================================================================
// Layer-2 pre-transform: Y2[n][o][b] = sum_k h1[n][k] * bases2[b][k][o].
// Thread = (node, o): o = gtid&15. acc float4 runs over the 4 bases.
// ===========================================================================
__global__ __launch_bounds__(256) void k_gemmY2(
    const float4* __restrict__ h1v,  // [N][16] float4
    const float* __restrict__ b2,    // bases2 [4][64][16]
    float4* __restrict__ y2v) {      // [N][16] float4 (o-major, b inner)
  const int gt = blockIdx.x * 256 + threadIdx.x;
  const int n = gt >> 4, o = gt & 15;
  float4 acc = {0, 0, 0, 0};
#pragma unroll 4
  for (int kb = 0; kb < 16; ++kb) {
    const float4 h4 = h1v[(size_t)n * 16 + kb];
#pragma unroll
    for (int r = 0; r < 4; ++r) {
      const int k = kb * 4 + r;
      const float hval = (r == 0) ? h4.x : (r == 1) ? h4.y : (r == 2) ? h4.z : h4.w;
      acc.x += hval * b2[0 * 1024 + k * 16 + o];
      acc.y += hval * b2[1 * 1024 + k * 16 + o];
      acc.z += hval * b2[2 * 1024 + k * 16 + o];
      acc.w += hval * b2[3 * 1024 + k * 16 + o];
    }
  }
  y2v[(size_t)n * 16 + o] = acc;
}

// ===========================================================================
// Layer-2 gather (final): out[d][o] = relu(bias2[o] +
//   sum_{e->d} norm_e * dot(coef2[t_e], Y2[src_e][o][:]))
// One wave per node; eslot = lane>>4, o = lane&15; 1-ahead prefetch.
// ===========================================================================
__global__ __launch_bounds__(256) void k_gather2(
    const int* __restrict__ rowp, const int2* __restrict__ s_edge,
    const float4* __restrict__ y2v,    // [N][16] float4
    const float4* __restrict__ coefv,  // [16]
    const float* __restrict__ bias2,   // [16]
    float* __restrict__ out) {         // [N][16]
  const int node = blockIdx.x * 4 + (threadIdx.x >> 6);
  const int lane = threadIdx.x & 63;
  const int eslot = lane >> 4, o = lane & 15;
  const int beg = rowp[node], end = rowp[node + 1];
  float acc = 0.f;
  int j = beg + eslot;
  int2 rec = make_int2(0, 0);
  float4 y = {0, 0, 0, 0};
  if (j < end) {
    rec = s_edge[j];
    y = y2v[(rec.x & 0xFFFF) * 16 + o];
  }
  while (j < end) {
    const int jn = j + 4;
    int2 rec_n = make_int2(0, 0);
    float4 y_n = {0, 0, 0, 0};
    if (jn < end) {
      rec_n = s_edge[jn];
      y_n = y2v[(rec_n.x & 0xFFFF) * 16 + o];
    }
    const float nm = __int_as_float(rec.y);
    const float4 c = coefv[(rec.x >> 16) & 15];
    acc += nm * (c.x * y.x + c.y * y.y + c.z * y.z + c.w * y.w);
    j = jn; rec = rec_n; y = y_n;
  }
  acc += __shfl_down(acc, 32, 64);
  acc += __shfl_down(acc, 16, 64);
  if (eslot == 0) out[(size_t)node * 16 + o] = fmaxf(acc + bias2[o], 0.f);
}

extern "C" void kernel_launch(void* const* d_in, const int* in_sizes, int n_in,
                              void* d_out, int out_size, void* d_ws, size_t ws_size,
                              hipStream_t stream) {
  const float* feats  = (const float*)d_in[0];
  const int*   src    = (const int*)d_in[1];
  const int*   dst    = (const int*)d_in[2];
  const int*   etype  = (const int*)d_in[3];
  const float* enorm  = (const float*)d_in[4];
  const float* bases1 = (const float*)d_in[5];
  const float* coef1  = (const float*)d_in[6];
  const float* bias1  = (const float*)d_in[7];
  const float* bases2 = (const float*)d_in[8];
  const float* coef2  = (const float*)d_in[9];
  const float* bias2  = (const float*)d_in[10];

  // Workspace: h1 (12.8 MB) | y2 (12.8 MB) | s_edge (6.4 MB) | rank (3.2 MB)
  //            | deg | rowp | bsum | boff   (~35.5 MB total)
  float* h1     = (float*)d_ws;                       // N*64 floats
  float* y2     = h1 + (size_t)N_NODES * 64;          // N*64 floats
  int2*  s_edge = (int2*)(y2 + (size_t)N_NODES * 64); // N_EDGES int2
  int*   rank   = (int*)(s_edge + N_EDGES);           // N_EDGES
  int*   deg    = rank + N_EDGES;                     // N
  int*   rowp   = deg + N_NODES;                      // N+1
  int*   bsum   = rowp + N_NODES + 1;                 // 64
  int*   boff   = bsum + 64;                          // 64

  const int SCAN_BLKS = (N_NODES + 1023) / 1024;  // 49

  hipMemsetAsync(deg, 0, N_NODES * sizeof(int), stream);

  k_hist<<<N_EDGES / 256, 256, 0, stream>>>(dst, deg, rank);
  k_scan1<<<SCAN_BLKS, 1024, 0, stream>>>(deg, rowp, bsum);
  k_scan2<<<1, 64, 0, stream>>>(bsum, boff, SCAN_BLKS);
  k_scan3<<<SCAN_BLKS, 1024, 0, stream>>>(rowp, boff);
  k_scatter<<<N_EDGES / 256, 256, 0, stream>>>(src, dst, etype, enorm,
                                               rowp, rank, s_edge);
  // Layer 1 fused: gather feats + (u @ bases1 + bias, relu) -> h1
  k_l1_fused<<<N_NODES / 4, 256, 0, stream>>>(
      rowp, s_edge, (const float4*)feats, (const float4*)coef1,
      bases1, bias1, h1);
  // Layer 2: pre-transform h1 -> Y2, gather Y2 -> out (+bias, relu)
  k_gemmY2<<<(N_NODES * 16) / 256, 256, 0, stream>>>(
      (const float4*)h1, bases2, (float4*)y2);
  k_gather2<<<N_NODES / 4, 256, 0, stream>>>(rowp, s_edge, (const float4*)y2,
                                             (const float4*)coef2, bias2,
                                             (float*)d_out);
}

// Round 5
// 277.978 us; speedup vs baseline: 1.4024x; 1.1600x over previous
//
#include <hip/hip_runtime.h>

#define N_NODES 50000
#define N_EDGES 800000
// IN=HID=64, OUT=16, N_RELS=16, N_BASES=4 (hard-coded below)

// ===========================================================================
// Histogram of dst + per-edge rank (return value of the atomic).
// ===========================================================================
__global__ __launch_bounds__(256) void k_hist(const int* __restrict__ dst,
                                              int* __restrict__ deg,
                                              int* __restrict__ rank) {
  int e = blockIdx.x * 256 + threadIdx.x;
  if (e < N_EDGES) rank[e] = atomicAdd(&deg[dst[e]], 1);
}

// Block-level inclusive scan of 1024 elems -> rowp[i+1]; block total -> bsum.
__global__ __launch_bounds__(1024) void k_scan1(const int* __restrict__ deg,
                                                int* __restrict__ rowp,
                                                int* __restrict__ bsum) {
  __shared__ int wsum[16];
  const int tid = threadIdx.x, lane = tid & 63, wid = tid >> 6;
  const int i = blockIdx.x * 1024 + tid;
  int v = (i < N_NODES) ? deg[i] : 0;
  int incl = v;
#pragma unroll
  for (int off = 1; off < 64; off <<= 1) {
    int t = __shfl_up(incl, off, 64);
    if (lane >= off) incl += t;
  }
  if (lane == 63) wsum[wid] = incl;
  __syncthreads();
  if (tid < 16) {
    int wi = wsum[tid];
#pragma unroll
    for (int off = 1; off < 16; off <<= 1) {
      int t = __shfl_up(wi, off, 64);
      if (lane >= off) wi += t;
    }
    wsum[tid] = wi;
  }
  __syncthreads();
  int woff = (wid > 0) ? wsum[wid - 1] : 0;
  int incl_all = incl + woff;
  if (i < N_NODES) rowp[i + 1] = incl_all;
  if (tid == 1023) bsum[blockIdx.x] = incl_all;
}

// scan2 folded in: each block redundantly reduces bsum[0..blockIdx-1].
__global__ __launch_bounds__(1024) void k_scan3(int* __restrict__ rowp,
                                                const int* __restrict__ bsum,
                                                int nblk) {
  __shared__ int s_off;
  const int tid = threadIdx.x;
  if (tid < 64) {
    int v = (tid < nblk && tid < blockIdx.x) ? bsum[tid] : 0;
#pragma unroll
    for (int off = 32; off >= 1; off >>= 1) v += __shfl_down(v, off, 64);
    if (tid == 0) s_off = v;
  }
  __syncthreads();
  const int i = blockIdx.x * 1024 + tid;
  if (i < N_NODES) rowp[i + 1] += s_off;
  if (i == 0) rowp[0] = 0;
}

// Atomic-free scatter into dst-sorted order; premultiplies the per-edge
// weights w_b = norm * coef[t][b] for BOTH layers (kills the dependent
// coef load in the gather inner loops).
__global__ __launch_bounds__(256) void k_scatter(
    const int* __restrict__ src, const int* __restrict__ dst,
    const int* __restrict__ ety, const float* __restrict__ enorm,
    const int* __restrict__ rowp, const int* __restrict__ rank,
    const float4* __restrict__ coef1v, const float4* __restrict__ coef2v,
    int* __restrict__ s_src, float4* __restrict__ s_w1,
    float4* __restrict__ s_w2) {
  int e = blockIdx.x * 256 + threadIdx.x;
  if (e >= N_EDGES) return;
  const int pos = rowp[dst[e]] + rank[e];
  const int t = ety[e];
  const float nm = enorm[e];
  const float4 c1 = coef1v[t], c2 = coef2v[t];
  s_src[pos] = src[e];
  s_w1[pos] = make_float4(nm * c1.x, nm * c1.y, nm * c1.z, nm * c1.w);
  s_w2[pos] = make_float4(nm * c2.x, nm * c2.y, nm * c2.z, nm * c2.w);
}

// ===========================================================================
// Fused layer (template over OUT width): block = 4 nodes, 4 waves.
// Phase A (gather, wave = node): eslot = lane>>4 (4 edges in flight,
//   1-ahead prefetch), ch = lane&15 (float4 over 64 channels):
//   u[n][b][k] = sum_e w_b(e) * x[src_e][k];  shfl-reduce -> transposed LDS
//   uT[q][node] (q = 64b + 4ch + r) so phase B feeds 4 nodes per ds_read_b128.
// Phase B (q-split GEMM): wave w owns q in [64w, 64w+64); partials reduced
//   across waves in LDS; bias + relu fused at the store.
// ===========================================================================
__device__ __forceinline__ void gather_to_uT(
    const int* __restrict__ rowp, const int* __restrict__ s_src,
    const float4* __restrict__ s_w, const float4* __restrict__ xv,
    float* __restrict__ uT, int node, int wid, int lane) {
  const int eslot = lane >> 4, ch = lane & 15;
  const int beg = rowp[node], end = rowp[node + 1];
  float4 a0 = {0, 0, 0, 0}, a1 = {0, 0, 0, 0}, a2 = {0, 0, 0, 0}, a3 = {0, 0, 0, 0};
  int j = beg + eslot;
  float4 w = {0, 0, 0, 0}, f = {0, 0, 0, 0};
  if (j < end) {
    w = s_w[j];
    f = xv[s_src[j] * 16 + ch];
  }
  while (j < end) {
    const int jn = j + 4;
    float4 w_n = {0, 0, 0, 0}, f_n = {0, 0, 0, 0};
    if (jn < end) {
      w_n = s_w[jn];
      f_n = xv[s_src[jn] * 16 + ch];
    }
    a0.x += w.x * f.x; a0.y += w.x * f.y; a0.z += w.x * f.z; a0.w += w.x * f.w;
    a1.x += w.y * f.x; a1.y += w.y * f.y; a1.z += w.y * f.z; a1.w += w.y * f.w;
    a2.x += w.z * f.x; a2.y += w.z * f.y; a2.z += w.z * f.z; a2.w += w.z * f.w;
    a3.x += w.w * f.x; a3.y += w.w * f.y; a3.z += w.w * f.z; a3.w += w.w * f.w;
    j = jn; w = w_n; f = f_n;
  }
#define RED1(x) x += __shfl_down(x, 32, 64); x += __shfl_down(x, 16, 64)
  RED1(a0.x); RED1(a0.y); RED1(a0.z); RED1(a0.w);
  RED1(a1.x); RED1(a1.y); RED1(a1.z); RED1(a1.w);
  RED1(a2.x); RED1(a2.y); RED1(a2.z); RED1(a2.w);
  RED1(a3.x); RED1(a3.y); RED1(a3.z); RED1(a3.w);
#undef RED1
  if (eslot == 0) {
    // uT[q][node], q = 64b + 4ch + r  (16 scalar writes; one-shot, conflicts ok)
    float* base = uT + (4 * ch) * 4 + wid;
#pragma unroll
    for (int r = 0; r < 4; ++r) base[(0 * 64 + r) * 4] = (&a0.x)[r];
#pragma unroll
    for (int r = 0; r < 4; ++r) base[(1 * 64 + r) * 4] = (&a1.x)[r];
#pragma unroll
    for (int r = 0; r < 4; ++r) base[(2 * 64 + r) * 4] = (&a2.x)[r];
#pragma unroll
    for (int r = 0; r < 4; ++r) base[(3 * 64 + r) * 4] = (&a3.x)[r];
  }
}

__global__ __launch_bounds__(256) void k_l1_fused(
    const int* __restrict__ rowp, const int* __restrict__ s_src,
    const float4* __restrict__ s_w1,
    const float4* __restrict__ xv,     // feats [N][16] float4
    const float* __restrict__ bases1,  // [256][64] flat
    const float* __restrict__ bias1,   // [64]
    float* __restrict__ h1) {          // [N][64]
  __shared__ float uT[256 * 4];        // 4 KB
  __shared__ float part[4 * 4 * 64];   // [w][n][o], 4 KB
  const int wid = threadIdx.x >> 6;
  const int lane = threadIdx.x & 63;
  const int node = blockIdx.x * 4 + wid;
  gather_to_uT(rowp, s_src, s_w1, xv, uT, node, wid, lane);
  __syncthreads();
  // Phase B: wave w owns q in [64w, 64w+64); lane = o (0..63).
  const int o = lane;
  float ac0 = 0.f, ac1 = 0.f, ac2 = 0.f, ac3 = 0.f;
#pragma unroll 4
  for (int qi = 0; qi < 64; ++qi) {
    const int q = (wid << 6) | qi;
    const float4 u4 = *(const float4*)&uT[q * 4];  // wave-uniform broadcast
    const float bb = bases1[q * 64 + o];           // 256B coalesced
    ac0 += u4.x * bb; ac1 += u4.y * bb; ac2 += u4.z * bb; ac3 += u4.w * bb;
  }
  part[(wid * 4 + 0) * 64 + o] = ac0;
  part[(wid * 4 + 1) * 64 + o] = ac1;
  part[(wid * 4 + 2) * 64 + o] = ac2;
  part[(wid * 4 + 3) * 64 + o] = ac3;
  __syncthreads();
  // Final: thread (n = wid, o) sums 4 wave-partials, bias + relu, store.
  const int n = wid;
  float s = part[(0 * 4 + n) * 64 + o] + part[(1 * 4 + n) * 64 + o] +
            part[(2 * 4 + n) * 64 + o] + part[(3 * 4 + n) * 64 + o];
  h1[(size_t)(blockIdx.x * 4 + n) * 64 + o] = fmaxf(s + bias1[o], 0.f);
}

__global__ __launch_bounds__(256) void k_l2_fused(
    const int* __restrict__ rowp, const int* __restrict__ s_src,
    const float4* __restrict__ s_w2,
    const float4* __restrict__ h1v,    // h1 [N][16] float4
    const float* __restrict__ bases2,  // [256][16] flat
    const float* __restrict__ bias2,   // [16]
    float* __restrict__ out) {         // [N][16]
  __shared__ float uT[256 * 4];            // 4 KB
  __shared__ float part2[4 * 4 * 4 * 17];  // [w][qsub][n][o pad17], ~4.3 KB
  const int wid = threadIdx.x >> 6;
  const int lane = threadIdx.x & 63;
  const int node = blockIdx.x * 4 + wid;
  gather_to_uT(rowp, s_src, s_w2, h1v, uT, node, wid, lane);
  __syncthreads();
  // Phase B: wave w owns q in [64w, 64w+64); lane = (qsub<<4)|o.
  const int qsub = lane >> 4, o = lane & 15;
  float ac0 = 0.f, ac1 = 0.f, ac2 = 0.f, ac3 = 0.f;
#pragma unroll 4
  for (int i = 0; i < 16; ++i) {
    const int q = (wid << 6) + (i << 2) + qsub;
    const float4 u4 = *(const float4*)&uT[q * 4];  // 4 addrs, 16-lane bcast
    const float bb = bases2[q * 16 + o];           // 256B coalesced
    ac0 += u4.x * bb; ac1 += u4.y * bb; ac2 += u4.z * bb; ac3 += u4.w * bb;
  }
  float* pp = &part2[((wid * 4 + qsub) * 4) * 17 + o];
  pp[0 * 17] = ac0; pp[1 * 17] = ac1; pp[2 * 17] = ac2; pp[3 * 17] = ac3;
  __syncthreads();
  if (threadIdx.x < 64) {
    const int n = threadIdx.x >> 4, o2 = threadIdx.x & 15;
    float s = 0.f;
#pragma unroll
    for (int w = 0; w < 4; ++w)
#pragma unroll
      for (int qs = 0; qs < 4; ++qs)
        s += part2[((w * 4 + qs) * 4 + n) * 17 + o2];
    out[(size_t)(blockIdx.x * 4 + n) * 16 + o2] = fmaxf(s + bias2[o2], 0.f);
  }
}

extern "C" void kernel_launch(void* const* d_in, const int* in_sizes, int n_in,
                              void* d_out, int out_size, void* d_ws, size_t ws_size,
                              hipStream_t stream) {
  const float* feats  = (const float*)d_in[0];
  const int*   src    = (const int*)d_in[1];
  const int*   dst    = (const int*)d_in[2];
  const int*   etype  = (const int*)d_in[3];
  const float* enorm  = (const float*)d_in[4];
  const float* bases1 = (const float*)d_in[5];
  const float* coef1  = (const float*)d_in[6];
  const float* bias1  = (const float*)d_in[7];
  const float* bases2 = (const float*)d_in[8];
  const float* coef2  = (const float*)d_in[9];
  const float* bias2  = (const float*)d_in[10];

  // Workspace (~45 MB): s_w1 | s_w2 (float4, 16B-aligned first) | h1 | s_src
  //                     | rank | deg | rowp | bsum
  float4* s_w1  = (float4*)d_ws;                      // E float4 (12.8 MB)
  float4* s_w2  = s_w1 + N_EDGES;                     // E float4 (12.8 MB)
  float*  h1    = (float*)(s_w2 + N_EDGES);           // N*64 floats (12.8 MB)
  int*    s_src = (int*)(h1 + (size_t)N_NODES * 64);  // E ints (3.2 MB)
  int*    rank  = s_src + N_EDGES;                    // E ints (3.2 MB)
  int*    deg   = rank + N_EDGES;                     // N
  int*    rowp  = deg + N_NODES;                      // N+1
  int*    bsum  = rowp + N_NODES + 1;                 // 64

  const int SCAN_BLKS = (N_NODES + 1023) / 1024;  // 49

  hipMemsetAsync(deg, 0, N_NODES * sizeof(int), stream);

  k_hist<<<N_EDGES / 256, 256, 0, stream>>>(dst, deg, rank);
  k_scan1<<<SCAN_BLKS, 1024, 0, stream>>>(deg, rowp, bsum);
  k_scan3<<<SCAN_BLKS, 1024, 0, stream>>>(rowp, bsum, SCAN_BLKS);
  k_scatter<<<N_EDGES / 256, 256, 0, stream>>>(
      src, dst, etype, enorm, rowp, rank, (const float4*)coef1,
      (const float4*)coef2, s_src, s_w1, s_w2);
  k_l1_fused<<<N_NODES / 4, 256, 0, stream>>>(
      rowp, s_src, s_w1, (const float4*)feats, bases1, bias1, h1);
  k_l2_fused<<<N_NODES / 4, 256, 0, stream>>>(
      rowp, s_src, s_w2, (const float4*)h1, bases2, bias2, (float*)d_out);
}

// Round 6
// 258.859 us; speedup vs baseline: 1.5060x; 1.0739x over previous
//
#include <hip/hip_runtime.h>

#define N_NODES 50000
#define N_EDGES 800000
// IN=HID=64, OUT=16, N_RELS=16, N_BASES=4 (hard-coded below)

// ---- bf16 helpers (RNE pack, shift-unpack) --------------------------------
__device__ __forceinline__ unsigned bf16rne(float x) {
  unsigned u = __float_as_uint(x);
  return (u + 0x7FFFu + ((u >> 16) & 1u)) >> 16;
}
__device__ __forceinline__ unsigned packbf2(float a, float b) {
  return bf16rne(a) | (bf16rne(b) << 16);
}
__device__ __forceinline__ float bflo(unsigned u) { return __uint_as_float(u << 16); }
__device__ __forceinline__ float bfhi(unsigned u) { return __uint_as_float(u & 0xFFFF0000u); }

// fp32 -> packed bf16 (pairs); used for feats. n4 = count of float4s.
__global__ __launch_bounds__(256) void k_tobf16(const float4* __restrict__ in,
                                                uint2* __restrict__ outp, int n4) {
  int i = blockIdx.x * 256 + threadIdx.x;
  if (i < n4) {
    float4 v = in[i];
    outp[i] = make_uint2(packbf2(v.x, v.y), packbf2(v.z, v.w));
  }
}

// ===========================================================================
// CSR build: histogram (+rank) -> hierarchical scan -> atomic-free scatter.
// ===========================================================================
__global__ __launch_bounds__(256) void k_hist(const int* __restrict__ dst,
                                              int* __restrict__ deg,
                                              int* __restrict__ rank) {
  int e = blockIdx.x * 256 + threadIdx.x;
  if (e < N_EDGES) rank[e] = atomicAdd(&deg[dst[e]], 1);
}

__global__ __launch_bounds__(1024) void k_scan1(const int* __restrict__ deg,
                                                int* __restrict__ rowp,
                                                int* __restrict__ bsum) {
  __shared__ int wsum[16];
  const int tid = threadIdx.x, lane = tid & 63, wid = tid >> 6;
  const int i = blockIdx.x * 1024 + tid;
  int v = (i < N_NODES) ? deg[i] : 0;
  int incl = v;
#pragma unroll
  for (int off = 1; off < 64; off <<= 1) {
    int t = __shfl_up(incl, off, 64);
    if (lane >= off) incl += t;
  }
  if (lane == 63) wsum[wid] = incl;
  __syncthreads();
  if (tid < 16) {
    int wi = wsum[tid];
#pragma unroll
    for (int off = 1; off < 16; off <<= 1) {
      int t = __shfl_up(wi, off, 64);
      if (lane >= off) wi += t;
    }
    wsum[tid] = wi;
  }
  __syncthreads();
  int woff = (wid > 0) ? wsum[wid - 1] : 0;
  int incl_all = incl + woff;
  if (i < N_NODES) rowp[i + 1] = incl_all;
  if (tid == 1023) bsum[blockIdx.x] = incl_all;
}

// Each block redundantly reduces bsum[0..blockIdx-1] (folded scan2).
__global__ __launch_bounds__(1024) void k_scan3(int* __restrict__ rowp,
                                                const int* __restrict__ bsum,
                                                int nblk) {
  __shared__ int s_off;
  const int tid = threadIdx.x;
  if (tid < 64) {
    int v = (tid < nblk && tid < blockIdx.x) ? bsum[tid] : 0;
#pragma unroll
    for (int off = 32; off >= 1; off >>= 1) v += __shfl_down(v, off, 64);
    if (tid == 0) s_off = v;
  }
  __syncthreads();
  const int i = blockIdx.x * 1024 + tid;
  if (i < N_NODES) rowp[i + 1] += s_off;
  if (i == 0) rowp[0] = 0;
}

// Scatter into dst-sorted order; premultiplied per-edge weights for both
// layers, compressed to bf16x4 (8 B each).
__global__ __launch_bounds__(256) void k_scatter(
    const int* __restrict__ src, const int* __restrict__ dst,
    const int* __restrict__ ety, const float* __restrict__ enorm,
    const int* __restrict__ rowp, const int* __restrict__ rank,
    const float4* __restrict__ coef1v, const float4* __restrict__ coef2v,
    int* __restrict__ s_src, uint2* __restrict__ s_w1,
    uint2* __restrict__ s_w2) {
  int e = blockIdx.x * 256 + threadIdx.x;
  if (e >= N_EDGES) return;
  const int pos = rowp[dst[e]] + rank[e];
  const int t = ety[e];
  const float nm = enorm[e];
  const float4 c1 = coef1v[t], c2 = coef2v[t];
  s_src[pos] = src[e];
  s_w1[pos] = make_uint2(packbf2(nm * c1.x, nm * c1.y), packbf2(nm * c1.z, nm * c1.w));
  s_w2[pos] = make_uint2(packbf2(nm * c2.x, nm * c2.y), packbf2(nm * c2.z, nm * c2.w));
}

// ===========================================================================
// Shared gather: u[n][b][k] = sum_{e->n} w_b(e) * x[src_e][k], bf16 inputs,
// fp32 accumulate. Wave = node; eslot = lane>>4 (4 edges in flight, 1-ahead
// prefetch), ch4 = lane&15 (channels 4ch4..4ch4+3, one 8 B bf16x4 load).
// Transposed+swizzled store to LDS: logical qi = 4ch4+c -> phys ch4+16c, so
// write banks are 4*ch4 (2-way, free). uT[q_phys][node] float.
// ===========================================================================
__device__ __forceinline__ void gather_to_uT(
    const int* __restrict__ rowp, const int* __restrict__ s_src,
    const uint2* __restrict__ s_w, const uint2* __restrict__ xv,
    float* __restrict__ uT, int node, int wid, int lane) {
  const int eslot = lane >> 4, ch4 = lane & 15;
  const int beg = rowp[node], end = rowp[node + 1];
  float4 a0 = {0, 0, 0, 0}, a1 = {0, 0, 0, 0}, a2 = {0, 0, 0, 0}, a3 = {0, 0, 0, 0};
  int j = beg + eslot;
  uint2 wp = {0, 0}, xp = {0, 0};
  if (j < end) {
    wp = s_w[j];
    xp = xv[s_src[j] * 16 + ch4];
  }
  while (j < end) {
    const int jn = j + 4;
    uint2 wpn = {0, 0}, xpn = {0, 0};
    if (jn < end) {
      wpn = s_w[jn];
      xpn = xv[s_src[jn] * 16 + ch4];
    }
    const float w0 = bflo(wp.x), w1 = bfhi(wp.x), w2 = bflo(wp.y), w3 = bfhi(wp.y);
    const float x0 = bflo(xp.x), x1 = bfhi(xp.x), x2 = bflo(xp.y), x3 = bfhi(xp.y);
    a0.x += w0 * x0; a0.y += w0 * x1; a0.z += w0 * x2; a0.w += w0 * x3;
    a1.x += w1 * x0; a1.y += w1 * x1; a1.z += w1 * x2; a1.w += w1 * x3;
    a2.x += w2 * x0; a2.y += w2 * x1; a2.z += w2 * x2; a2.w += w2 * x3;
    a3.x += w3 * x0; a3.y += w3 * x1; a3.z += w3 * x2; a3.w += w3 * x3;
    j = jn; wp = wpn; xp = xpn;
  }
#define RED1(x) x += __shfl_down(x, 32, 64); x += __shfl_down(x, 16, 64)
  RED1(a0.x); RED1(a0.y); RED1(a0.z); RED1(a0.w);
  RED1(a1.x); RED1(a1.y); RED1(a1.z); RED1(a1.w);
  RED1(a2.x); RED1(a2.y); RED1(a2.z); RED1(a2.w);
  RED1(a3.x); RED1(a3.y); RED1(a3.z); RED1(a3.w);
#undef RED1
  if (eslot == 0) {
    // uT index = (64b + ch4 + 16c)*4 + wid = (4ch4 + wid) + 64c + 256b
    float* base = uT + ch4 * 4 + wid;
#pragma unroll
    for (int c = 0; c < 4; ++c) {
      base[c * 64 + 0 * 256] = (&a0.x)[c];
      base[c * 64 + 1 * 256] = (&a1.x)[c];
      base[c * 64 + 2 * 256] = (&a2.x)[c];
      base[c * 64 + 3 * 256] = (&a3.x)[c];
    }
  }
}

// ===========================================================================
// Fused layer 1: gather -> uT, then q-split GEMM with float4 bases loads.
// Phase B lane = (qsub = lane>>4, o4 = lane&15): 16 iters, each:
//   1 ds_read_b128 (u for 4 nodes) + 1 global float4 (bases1[q][4o4..]) +
//   16 FMA. Partials over 16 (wid,qsub) groups reduced in LDS.
// h1 emitted as bf16 for the layer-2 gather.
// ===========================================================================
__global__ __launch_bounds__(256) void k_l1_fused(
    const int* __restrict__ rowp, const int* __restrict__ s_src,
    const uint2* __restrict__ s_w1, const uint2* __restrict__ xbf,
    const float4* __restrict__ bases1v,  // [256][16] float4
    const float* __restrict__ bias1,     // [64]
    unsigned short* __restrict__ h1bf) { // [N][64] bf16
  __shared__ float uT[256 * 4];        // 4 KB
  __shared__ float part[16 * 4 * 64];  // [g][n][o], 16 KB
  const int wid = threadIdx.x >> 6, lane = threadIdx.x & 63;
  gather_to_uT(rowp, s_src, s_w1, xbf, uT, blockIdx.x * 4 + wid, wid, lane);
  __syncthreads();
  const int o4 = lane & 15, qsub = lane >> 4;
  float4 acc[4] = {{0, 0, 0, 0}, {0, 0, 0, 0}, {0, 0, 0, 0}, {0, 0, 0, 0}};
#pragma unroll 4
  for (int i = 0; i < 16; ++i) {
    const int p = (i << 2) | qsub;                       // phys q within 64
    const float4 u4 = *(const float4*)&uT[(((wid << 6) | p)) << 2];
    const int qi = ((p & 15) << 2) | (p >> 4);           // un-swizzle
    const float4 bb = bases1v[(((wid << 6) | qi) << 4) + o4];
    acc[0].x += u4.x * bb.x; acc[0].y += u4.x * bb.y; acc[0].z += u4.x * bb.z; acc[0].w += u4.x * bb.w;
    acc[1].x += u4.y * bb.x; acc[1].y += u4.y * bb.y; acc[1].z += u4.y * bb.z; acc[1].w += u4.y * bb.w;
    acc[2].x += u4.z * bb.x; acc[2].y += u4.z * bb.y; acc[2].z += u4.z * bb.z; acc[2].w += u4.z * bb.w;
    acc[3].x += u4.w * bb.x; acc[3].y += u4.w * bb.y; acc[3].z += u4.w * bb.z; acc[3].w += u4.w * bb.w;
  }
  const int g = (wid << 2) | qsub;  // 0..15
#pragma unroll
  for (int n = 0; n < 4; ++n)
    *(float4*)&part[(((g << 2) | n) << 6) + (o4 << 2)] = acc[n];
  __syncthreads();
  const int n = threadIdx.x >> 6, o = threadIdx.x & 63;
  float s = 0.f;
#pragma unroll
  for (int g2 = 0; g2 < 16; ++g2) s += part[(((g2 << 2) | n) << 6) + o];
  const float r = fmaxf(s + bias1[o], 0.f);
  h1bf[(size_t)(blockIdx.x * 4 + n) * 64 + o] = (unsigned short)bf16rne(r);
}

// ===========================================================================
// Fused layer 2: gather h1(bf16) -> uT, q-split GEMM (OUT=16), fp32 out.
// Phase B lane = (qsub = lane>>4, o = lane&15); scalar bases2 loads.
// ===========================================================================
__global__ __launch_bounds__(256) void k_l2_fused(
    const int* __restrict__ rowp, const int* __restrict__ s_src,
    const uint2* __restrict__ s_w2, const uint2* __restrict__ h1bf,
    const float* __restrict__ bases2,  // [256][16]
    const float* __restrict__ bias2,   // [16]
    float* __restrict__ out) {         // [N][16]
  __shared__ float uT[256 * 4];        // 4 KB
  __shared__ float part2[16 * 4 * 17]; // [g][n][o pad17], ~4.3 KB
  const int wid = threadIdx.x >> 6, lane = threadIdx.x & 63;
  gather_to_uT(rowp, s_src, s_w2, h1bf, uT, blockIdx.x * 4 + wid, wid, lane);
  __syncthreads();
  const int o = lane & 15, qsub = lane >> 4;
  float ac0 = 0.f, ac1 = 0.f, ac2 = 0.f, ac3 = 0.f;
#pragma unroll 4
  for (int i = 0; i < 16; ++i) {
    const int p = (i << 2) | qsub;
    const float4 u4 = *(const float4*)&uT[(((wid << 6) | p)) << 2];
    const int qi = ((p & 15) << 2) | (p >> 4);
    const float bb = bases2[(((wid << 6) | qi) << 4) + o];
    ac0 += u4.x * bb; ac1 += u4.y * bb; ac2 += u4.z * bb; ac3 += u4.w * bb;
  }
  const int g = (wid << 2) | qsub;
  part2[((g << 2) | 0) * 17 + o] = ac0;
  part2[((g << 2) | 1) * 17 + o] = ac1;
  part2[((g << 2) | 2) * 17 + o] = ac2;
  part2[((g << 2) | 3) * 17 + o] = ac3;
  __syncthreads();
  if (threadIdx.x < 64) {
    const int n = threadIdx.x >> 4, o2 = threadIdx.x & 15;
    float s = 0.f;
#pragma unroll
    for (int g2 = 0; g2 < 16; ++g2) s += part2[((g2 << 2) | n) * 17 + o2];
    out[(size_t)(blockIdx.x * 4 + n) * 16 + o2] = fmaxf(s + bias2[o2], 0.f);
  }
}

extern "C" void kernel_launch(void* const* d_in, const int* in_sizes, int n_in,
                              void* d_out, int out_size, void* d_ws, size_t ws_size,
                              hipStream_t stream) {
  const float* feats  = (const float*)d_in[0];
  const int*   src    = (const int*)d_in[1];
  const int*   dst    = (const int*)d_in[2];
  const int*   etype  = (const int*)d_in[3];
  const float* enorm  = (const float*)d_in[4];
  const float* bases1 = (const float*)d_in[5];
  const float* coef1  = (const float*)d_in[6];
  const float* bias1  = (const float*)d_in[7];
  const float* bases2 = (const float*)d_in[8];
  const float* coef2  = (const float*)d_in[9];
  const float* bias2  = (const float*)d_in[10];

  // Workspace (~33 MB): xbf | h1bf (bf16 rows) | s_w1 | s_w2 | s_src | rank
  //                     | deg | rowp | bsum
  uint2* xbf   = (uint2*)d_ws;                        // N*16 uint2 (6.4 MB)
  uint2* h1bf  = xbf + (size_t)N_NODES * 16;          // N*16 uint2 (6.4 MB)
  uint2* s_w1  = h1bf + (size_t)N_NODES * 16;         // E uint2 (6.4 MB)
  uint2* s_w2  = s_w1 + N_EDGES;                      // E uint2 (6.4 MB)
  int*   s_src = (int*)(s_w2 + N_EDGES);              // E ints (3.2 MB)
  int*   rank  = s_src + N_EDGES;                     // E ints (3.2 MB)
  int*   deg   = rank + N_EDGES;                      // N
  int*   rowp  = deg + N_NODES;                       // N+1
  int*   bsum  = rowp + N_NODES + 1;                  // 64

  const int SCAN_BLKS = (N_NODES + 1023) / 1024;  // 49

  hipMemsetAsync(deg, 0, N_NODES * sizeof(int), stream);

  k_tobf16<<<(N_NODES * 16 + 255) / 256, 256, 0, stream>>>(
      (const float4*)feats, xbf, N_NODES * 16);
  k_hist<<<N_EDGES / 256, 256, 0, stream>>>(dst, deg, rank);
  k_scan1<<<SCAN_BLKS, 1024, 0, stream>>>(deg, rowp, bsum);
  k_scan3<<<SCAN_BLKS, 1024, 0, stream>>>(rowp, bsum, SCAN_BLKS);
  k_scatter<<<N_EDGES / 256, 256, 0, stream>>>(
      src, dst, etype, enorm, rowp, rank, (const float4*)coef1,
      (const float4*)coef2, s_src, s_w1, s_w2);
  k_l1_fused<<<N_NODES / 4, 256, 0, stream>>>(
      rowp, s_src, s_w1, xbf, (const float4*)bases1, bias1,
      (unsigned short*)h1bf);
  k_l2_fused<<<N_NODES / 4, 256, 0, stream>>>(
      rowp, s_src, s_w2, h1bf, bases2, bias2, (float*)d_out);
}

// Round 7
// 233.744 us; speedup vs baseline: 1.6678x; 1.1074x over previous
//
#include <hip/hip_runtime.h>

#define N_NODES 50000
#define N_EDGES 800000
// IN=HID=64, OUT=16, N_RELS=16, N_BASES=4 (hard-coded below)

typedef __attribute__((ext_vector_type(8))) short bf16x8;
typedef __attribute__((ext_vector_type(4))) float f32x4;

// ---- bf16 helpers (RNE pack, shift-unpack) --------------------------------
__device__ __forceinline__ unsigned bf16rne(float x) {
  unsigned u = __float_as_uint(x);
  return (u + 0x7FFFu + ((u >> 16) & 1u)) >> 16;
}
__device__ __forceinline__ unsigned packbf2(float a, float b) {
  return bf16rne(a) | (bf16rne(b) << 16);
}
__device__ __forceinline__ float bflo(unsigned u) { return __uint_as_float(u << 16); }
__device__ __forceinline__ float bfhi(unsigned u) { return __uint_as_float(u & 0xFFFF0000u); }

// ===========================================================================
// Prep: blocks 0..3124 pack feats fp32->bf16 rows; block 3125 builds the
// bf16 transposed bases: b1T[o][q] (64x256), b2T[o][q] (16x256).
// ===========================================================================
__global__ __launch_bounds__(256) void k_prep(
    const float4* __restrict__ feats4, uint2* __restrict__ xbf,
    const float* __restrict__ bases1, const float* __restrict__ bases2,
    unsigned short* __restrict__ b1T, unsigned short* __restrict__ b2T) {
  if (blockIdx.x < 3125) {
    int i = blockIdx.x * 256 + threadIdx.x;  // over 800000 float4s
    float4 v = feats4[i];
    xbf[i] = make_uint2(packbf2(v.x, v.y), packbf2(v.z, v.w));
  } else {
    for (int idx = threadIdx.x; idx < 64 * 256; idx += 256) {
      int o = idx >> 8, q = idx & 255;
      b1T[o * 256 + q] = (unsigned short)bf16rne(bases1[q * 64 + o]);
    }
    for (int idx = threadIdx.x; idx < 16 * 256; idx += 256) {
      int o = idx >> 8, q = idx & 255;
      b2T[o * 256 + q] = (unsigned short)bf16rne(bases2[q * 16 + o]);
    }
  }
}

// ===========================================================================
// CSR build: histogram (+rank) -> hierarchical scan -> atomic-free scatter.
// ===========================================================================
__global__ __launch_bounds__(256) void k_hist(const int* __restrict__ dst,
                                              int* __restrict__ deg,
                                              int* __restrict__ rank) {
  int e = blockIdx.x * 256 + threadIdx.x;
  if (e < N_EDGES) rank[e] = atomicAdd(&deg[dst[e]], 1);
}

__global__ __launch_bounds__(1024) void k_scan1(const int* __restrict__ deg,
                                                int* __restrict__ rowp,
                                                int* __restrict__ bsum) {
  __shared__ int wsum[16];
  const int tid = threadIdx.x, lane = tid & 63, wid = tid >> 6;
  const int i = blockIdx.x * 1024 + tid;
  int v = (i < N_NODES) ? deg[i] : 0;
  int incl = v;
#pragma unroll
  for (int off = 1; off < 64; off <<= 1) {
    int t = __shfl_up(incl, off, 64);
    if (lane >= off) incl += t;
  }
  if (lane == 63) wsum[wid] = incl;
  __syncthreads();
  if (tid < 16) {
    int wi = wsum[tid];
#pragma unroll
    for (int off = 1; off < 16; off <<= 1) {
      int t = __shfl_up(wi, off, 64);
      if (lane >= off) wi += t;
    }
    wsum[tid] = wi;
  }
  __syncthreads();
  int woff = (wid > 0) ? wsum[wid - 1] : 0;
  int incl_all = incl + woff;
  if (i < N_NODES) rowp[i + 1] = incl_all;
  if (tid == 1023) bsum[blockIdx.x] = incl_all;
}

__global__ __launch_bounds__(1024) void k_scan3(int* __restrict__ rowp,
                                                const int* __restrict__ bsum,
                                                int nblk) {
  __shared__ int s_off;
  const int tid = threadIdx.x;
  if (tid < 64) {
    int v = (tid < nblk && tid < blockIdx.x) ? bsum[tid] : 0;
#pragma unroll
    for (int off = 32; off >= 1; off >>= 1) v += __shfl_down(v, off, 64);
    if (tid == 0) s_off = v;
  }
  __syncthreads();
  const int i = blockIdx.x * 1024 + tid;
  if (i < N_NODES) rowp[i + 1] += s_off;
  if (i == 0) rowp[0] = 0;
}

// 8 B records: (src | ety<<16, norm fp32 bits) into dst-sorted order.
__global__ __launch_bounds__(256) void k_scatter(
    const int* __restrict__ src, const int* __restrict__ dst,
    const int* __restrict__ ety, const float* __restrict__ enorm,
    const int* __restrict__ rowp, const int* __restrict__ rank,
    uint2* __restrict__ s_edge) {
  int e = blockIdx.x * 256 + threadIdx.x;
  if (e >= N_EDGES) return;
  const int pos = rowp[dst[e]] + rank[e];
  s_edge[pos] = make_uint2((unsigned)src[e] | ((unsigned)ety[e] << 16),
                           __float_as_uint(enorm[e]));
}

// ===========================================================================
// Gather one node's u into the MFMA A-tile (bf16), fp32 accumulate.
// Wave = node; eslot = lane>>4 (4 edges in flight, 1-ahead prefetch),
// ch4 = lane&15 (channels 4ch4..4ch4+3, one 8 B bf16x4 load).
// w_b = norm * coefLDS[t][b] (LDS broadcast within an eslot row).
// uA row m (pad 264 bf16): k = q = 64b + 4ch4 + c.
// ===========================================================================
#define ROWB 264
__device__ __forceinline__ void gather_node(
    const int* __restrict__ rowp, const uint2* __restrict__ s_edge,
    const uint2* __restrict__ xv, const float4* __restrict__ coefLDS,
    unsigned short* __restrict__ uA, int node, int m, int lane) {
  const int eslot = lane >> 4, ch4 = lane & 15;
  const int beg = rowp[node], end = rowp[node + 1];
  float4 a0 = {0, 0, 0, 0}, a1 = {0, 0, 0, 0}, a2 = {0, 0, 0, 0}, a3 = {0, 0, 0, 0};
  int j = beg + eslot;
  uint2 rec = {0, 0}, xp = {0, 0};
  if (j < end) {
    rec = s_edge[j];
    xp = xv[(rec.x & 0xFFFF) * 16 + ch4];
  }
  while (j < end) {
    const int jn = j + 4;
    uint2 rec_n = {0, 0}, xp_n = {0, 0};
    if (jn < end) {
      rec_n = s_edge[jn];
      xp_n = xv[(rec_n.x & 0xFFFF) * 16 + ch4];
    }
    const float nm = __uint_as_float(rec.y);
    const float4 c = coefLDS[rec.x >> 16];  // broadcast within eslot row
    const float w0 = nm * c.x, w1 = nm * c.y, w2 = nm * c.z, w3 = nm * c.w;
    const float x0 = bflo(xp.x), x1 = bfhi(xp.x), x2 = bflo(xp.y), x3 = bfhi(xp.y);
    a0.x += w0 * x0; a0.y += w0 * x1; a0.z += w0 * x2; a0.w += w0 * x3;
    a1.x += w1 * x0; a1.y += w1 * x1; a1.z += w1 * x2; a1.w += w1 * x3;
    a2.x += w2 * x0; a2.y += w2 * x1; a2.z += w2 * x2; a2.w += w2 * x3;
    a3.x += w3 * x0; a3.y += w3 * x1; a3.z += w3 * x2; a3.w += w3 * x3;
    j = jn; rec = rec_n; xp = xp_n;
  }
#define RED1(x) x += __shfl_down(x, 32, 64); x += __shfl_down(x, 16, 64)
  RED1(a0.x); RED1(a0.y); RED1(a0.z); RED1(a0.w);
  RED1(a1.x); RED1(a1.y); RED1(a1.z); RED1(a1.w);
  RED1(a2.x); RED1(a2.y); RED1(a2.z); RED1(a2.w);
  RED1(a3.x); RED1(a3.y); RED1(a3.z); RED1(a3.w);
#undef RED1
  if (eslot == 0) {
    // 4 x 8 B writes: banks 2*ch4 (+even) -> conflict-free across 16 lanes
    unsigned short* row = uA + m * ROWB + 4 * ch4;
    *(uint2*)(row + 0 * 64) = make_uint2(packbf2(a0.x, a0.y), packbf2(a0.z, a0.w));
    *(uint2*)(row + 1 * 64) = make_uint2(packbf2(a1.x, a1.y), packbf2(a1.z, a1.w));
    *(uint2*)(row + 2 * 64) = make_uint2(packbf2(a2.x, a2.y), packbf2(a2.z, a2.w));
    *(uint2*)(row + 3 * 64) = make_uint2(packbf2(a3.x, a3.y), packbf2(a3.z, a3.w));
  }
}

// ===========================================================================
// Fused layer 1: 16 nodes/block, 4 waves. Each wave gathers 4 nodes into the
// shared A-tile; then MFMA [16x256]@[256x64]: wave w = n-tile w, 8 k-steps.
// Epilogue: bias+relu via LDS cmat, pack bf16, coalesced uint2 stores.
// ===========================================================================
__global__ __launch_bounds__(256) void k_l1_fused(
    const int* __restrict__ rowp, const uint2* __restrict__ s_edge,
    const uint2* __restrict__ xbf, const float* __restrict__ coef1,
    const unsigned short* __restrict__ b1T,  // [64][256] bf16
    const float* __restrict__ bias1,         // [64]
    uint2* __restrict__ h1bf) {              // [N][16] uint2 = [N][64] bf16
  __shared__ __align__(16) unsigned short uA[16 * ROWB];  // 8.25 KB
  __shared__ float coefs[64];
  __shared__ float cmat[16 * 68];  // 4.25 KB
  const int wid = threadIdx.x >> 6, lane = threadIdx.x & 63;
  if (threadIdx.x < 64) coefs[threadIdx.x] = coef1[threadIdx.x];
  __syncthreads();
  const int nbase = blockIdx.x * 16;
#pragma unroll
  for (int jn = 0; jn < 4; ++jn) {
    const int m = wid * 4 + jn;
    gather_node(rowp, s_edge, xbf, (const float4*)coefs, uA, nbase + m, m, lane);
  }
  __syncthreads();
  // MFMA: wave wid handles n-tile wid (o = 16*wid .. +15).
  const int nloc = lane & 15, kgrp = lane >> 4;
  f32x4 acc = {0.f, 0.f, 0.f, 0.f};
#pragma unroll
  for (int ks = 0; ks < 8; ++ks) {
    const int k0 = ks * 32 + kgrp * 8;
    const bf16x8 a = *(const bf16x8*)&uA[nloc * ROWB + k0];
    const bf16x8 b = *(const bf16x8*)&b1T[(wid * 16 + nloc) * 256 + k0];
    acc = __builtin_amdgcn_mfma_f32_16x16x32_bf16(a, b, acc, 0, 0, 0);
  }
  // D[m=(lane>>4)*4+r][n=lane&15]; o = wid*16 + n. bias+relu -> cmat.
  {
    const int o = wid * 16 + nloc;
    const float bs = bias1[o];
#pragma unroll
    for (int r = 0; r < 4; ++r) {
      const int m = (lane >> 4) * 4 + r;
      cmat[m * 68 + o] = fmaxf(acc[r] + bs, 0.f);
    }
  }
  __syncthreads();
  const int nl = threadIdx.x >> 4, ch4 = threadIdx.x & 15;
  const float* cr = &cmat[nl * 68 + 4 * ch4];
  h1bf[(size_t)(nbase + nl) * 16 + ch4] =
      make_uint2(packbf2(cr[0], cr[1]), packbf2(cr[2], cr[3]));
}

// ===========================================================================
// Fused layer 2: same A-tile build from h1bf; MFMA [16x256]@[256x16] with
// K split across the 4 waves (2 k-steps each); LDS partial reduce; fp32 out.
// ===========================================================================
__global__ __launch_bounds__(256) void k_l2_fused(
    const int* __restrict__ rowp, const uint2* __restrict__ s_edge,
    const uint2* __restrict__ h1bf, const float* __restrict__ coef2,
    const unsigned short* __restrict__ b2T,  // [16][256] bf16
    const float* __restrict__ bias2,         // [16]
    float* __restrict__ out) {               // [N][16]
  __shared__ __align__(16) unsigned short uA[16 * ROWB];  // 8.25 KB
  __shared__ float coefs[64];
  __shared__ float pmat[4 * 16 * 17];  // 4.25 KB
  const int wid = threadIdx.x >> 6, lane = threadIdx.x & 63;
  if (threadIdx.x < 64) coefs[threadIdx.x] = coef2[threadIdx.x];
  __syncthreads();
  const int nbase = blockIdx.x * 16;
#pragma unroll
  for (int jn = 0; jn < 4; ++jn) {
    const int m = wid * 4 + jn;
    gather_node(rowp, s_edge, h1bf, (const float4*)coefs, uA, nbase + m, m, lane);
  }
  __syncthreads();
  const int nloc = lane & 15, kgrp = lane >> 4;
  f32x4 acc = {0.f, 0.f, 0.f, 0.f};
#pragma unroll
  for (int i = 0; i < 2; ++i) {
    const int k0 = (wid * 2 + i) * 32 + kgrp * 8;
    const bf16x8 a = *(const bf16x8*)&uA[nloc * ROWB + k0];
    const bf16x8 b = *(const bf16x8*)&b2T[nloc * 256 + k0];
    acc = __builtin_amdgcn_mfma_f32_16x16x32_bf16(a, b, acc, 0, 0, 0);
  }
#pragma unroll
  for (int r = 0; r < 4; ++r) {
    const int m = (lane >> 4) * 4 + r;
    pmat[(wid * 16 + m) * 17 + nloc] = acc[r];
  }
  __syncthreads();
  const int m = threadIdx.x >> 4, n = threadIdx.x & 15;
  float s = pmat[(0 * 16 + m) * 17 + n] + pmat[(1 * 16 + m) * 17 + n] +
            pmat[(2 * 16 + m) * 17 + n] + pmat[(3 * 16 + m) * 17 + n];
  out[(size_t)(nbase + m) * 16 + n] = fmaxf(s + bias2[n], 0.f);
}

extern "C" void kernel_launch(void* const* d_in, const int* in_sizes, int n_in,
                              void* d_out, int out_size, void* d_ws, size_t ws_size,
                              hipStream_t stream) {
  const float* feats  = (const float*)d_in[0];
  const int*   src    = (const int*)d_in[1];
  const int*   dst    = (const int*)d_in[2];
  const int*   etype  = (const int*)d_in[3];
  const float* enorm  = (const float*)d_in[4];
  const float* bases1 = (const float*)d_in[5];
  const float* coef1  = (const float*)d_in[6];
  const float* bias1  = (const float*)d_in[7];
  const float* bases2 = (const float*)d_in[8];
  const float* coef2  = (const float*)d_in[9];
  const float* bias2  = (const float*)d_in[10];

  // Workspace (~23 MB): xbf | h1bf | s_edge | rank | b1T | b2T | deg | rowp | bsum
  uint2* xbf    = (uint2*)d_ws;                       // N*16 uint2 (6.4 MB)
  uint2* h1bf   = xbf + (size_t)N_NODES * 16;         // N*16 uint2 (6.4 MB)
  uint2* s_edge = h1bf + (size_t)N_NODES * 16;        // E uint2 (6.4 MB)
  int*   rank   = (int*)(s_edge + N_EDGES);           // E ints (3.2 MB)
  unsigned short* b1T = (unsigned short*)(rank + N_EDGES);  // 16384 (32 KB)
  unsigned short* b2T = b1T + 64 * 256;               // 4096 (8 KB)
  int*   deg    = (int*)(b2T + 16 * 256);             // N
  int*   rowp   = deg + N_NODES;                      // N+1
  int*   bsum   = rowp + N_NODES + 1;                 // 64

  const int SCAN_BLKS = (N_NODES + 1023) / 1024;  // 49

  hipMemsetAsync(deg, 0, N_NODES * sizeof(int), stream);

  k_prep<<<3126, 256, 0, stream>>>((const float4*)feats, xbf, bases1, bases2,
                                   b1T, b2T);
  k_hist<<<N_EDGES / 256, 256, 0, stream>>>(dst, deg, rank);
  k_scan1<<<SCAN_BLKS, 1024, 0, stream>>>(deg, rowp, bsum);
  k_scan3<<<SCAN_BLKS, 1024, 0, stream>>>(rowp, bsum, SCAN_BLKS);
  k_scatter<<<N_EDGES / 256, 256, 0, stream>>>(src, dst, etype, enorm,
                                               rowp, rank, s_edge);
  k_l1_fused<<<N_NODES / 16, 256, 0, stream>>>(rowp, s_edge, xbf, coef1,
                                               b1T, bias1, h1bf);
  k_l2_fused<<<N_NODES / 16, 256, 0, stream>>>(rowp, s_edge, h1bf, coef2,
                                               b2T, bias2, (float*)d_out);
}

// Round 8
// 213.676 us; speedup vs baseline: 1.8244x; 1.0939x over previous
//
#include <hip/hip_runtime.h>

#define N_NODES 50000
#define N_EDGES 800000
// IN=HID=64, OUT=16, N_RELS=16, N_BASES=4 (hard-coded below)

typedef __attribute__((ext_vector_type(8))) short bf16x8;
typedef __attribute__((ext_vector_type(4))) float f32x4;

// ---- bf16 helpers (RNE pack, shift-unpack) --------------------------------
__device__ __forceinline__ unsigned bf16rne(float x) {
  unsigned u = __float_as_uint(x);
  return (u + 0x7FFFu + ((u >> 16) & 1u)) >> 16;
}
__device__ __forceinline__ unsigned packbf2(float a, float b) {
  return bf16rne(a) | (bf16rne(b) << 16);
}
__device__ __forceinline__ float bflo(unsigned u) { return __uint_as_float(u << 16); }
__device__ __forceinline__ float bfhi(unsigned u) { return __uint_as_float(u & 0xFFFF0000u); }

// ===========================================================================
// Merged prep + histogram. feats float4 count (50000*64/4) == N_EDGES ==
// 800000, so blocks 0..3124 use one index for both the bf16 pack and the
// dst histogram (+rank). Block 3125 builds the bf16 B-matrices:
//   b1T[o][q] (64x256)  : bases1[q][o]          (layer-1 MFMA B operand)
//   b2p[j][k] (64x64)   : j = o*4+b -> bases2[b][k][o]  (Y2 MFMA B operand)
// ===========================================================================
__global__ __launch_bounds__(256) void k_prep_hist(
    const float4* __restrict__ feats4, uint2* __restrict__ xbf,
    const float* __restrict__ bases1, const float* __restrict__ bases2,
    unsigned short* __restrict__ b1T, unsigned short* __restrict__ b2p,
    const int* __restrict__ dst, int* __restrict__ deg,
    int* __restrict__ rank) {
  if (blockIdx.x < 3125) {
    const int i = blockIdx.x * 256 + threadIdx.x;  // < 800000
    float4 v = feats4[i];
    xbf[i] = make_uint2(packbf2(v.x, v.y), packbf2(v.z, v.w));
    rank[i] = atomicAdd(&deg[dst[i]], 1);
  } else {
    for (int idx = threadIdx.x; idx < 64 * 256; idx += 256) {
      int o = idx >> 8, q = idx & 255;
      b1T[idx] = (unsigned short)bf16rne(bases1[q * 64 + o]);
    }
    for (int idx = threadIdx.x; idx < 64 * 64; idx += 256) {
      int j = idx >> 6, k = idx & 63;
      int o = j >> 2, b = j & 3;
      b2p[idx] = (unsigned short)bf16rne(bases2[b * 1024 + k * 16 + o]);
    }
  }
}

// ===========================================================================
// Hierarchical exclusive scan -> rowp.
// ===========================================================================
__global__ __launch_bounds__(1024) void k_scan1(const int* __restrict__ deg,
                                                int* __restrict__ rowp,
                                                int* __restrict__ bsum) {
  __shared__ int wsum[16];
  const int tid = threadIdx.x, lane = tid & 63, wid = tid >> 6;
  const int i = blockIdx.x * 1024 + tid;
  int v = (i < N_NODES) ? deg[i] : 0;
  int incl = v;
#pragma unroll
  for (int off = 1; off < 64; off <<= 1) {
    int t = __shfl_up(incl, off, 64);
    if (lane >= off) incl += t;
  }
  if (lane == 63) wsum[wid] = incl;
  __syncthreads();
  if (tid < 16) {
    int wi = wsum[tid];
#pragma unroll
    for (int off = 1; off < 16; off <<= 1) {
      int t = __shfl_up(wi, off, 64);
      if (lane >= off) wi += t;
    }
    wsum[tid] = wi;
  }
  __syncthreads();
  int woff = (wid > 0) ? wsum[wid - 1] : 0;
  int incl_all = incl + woff;
  if (i < N_NODES) rowp[i + 1] = incl_all;
  if (tid == 1023) bsum[blockIdx.x] = incl_all;
}

__global__ __launch_bounds__(1024) void k_scan3(int* __restrict__ rowp,
                                                const int* __restrict__ bsum,
                                                int nblk) {
  __shared__ int s_off;
  const int tid = threadIdx.x;
  if (tid < 64) {
    int v = (tid < nblk && tid < blockIdx.x) ? bsum[tid] : 0;
#pragma unroll
    for (int off = 32; off >= 1; off >>= 1) v += __shfl_down(v, off, 64);
    if (tid == 0) s_off = v;
  }
  __syncthreads();
  const int i = blockIdx.x * 1024 + tid;
  if (i < N_NODES) rowp[i + 1] += s_off;
  if (i == 0) rowp[0] = 0;
}

// 8 B records: (src | ety<<16, norm fp32 bits) into dst-sorted order.
__global__ __launch_bounds__(256) void k_scatter(
    const int* __restrict__ src, const int* __restrict__ dst,
    const int* __restrict__ ety, const float* __restrict__ enorm,
    const int* __restrict__ rowp, const int* __restrict__ rank,
    uint2* __restrict__ s_edge) {
  int e = blockIdx.x * 256 + threadIdx.x;
  if (e >= N_EDGES) return;
  const int pos = rowp[dst[e]] + rank[e];
  s_edge[pos] = make_uint2((unsigned)src[e] | ((unsigned)ety[e] << 16),
                           __float_as_uint(enorm[e]));
}

// ===========================================================================
// Gather one node's u into the MFMA A-tile (bf16), fp32 accumulate.
// Wave = node; eslot = lane>>4, ch4 = lane&15 (channels 4ch4..+3, 8 B load).
// 2-AHEAD pipeline: rec fetched at distance 2, x at distance 1 using the rec
// that arrived last iteration -> rec->x dependency is off the critical path.
// ===========================================================================
#define ROWB 264
__device__ __forceinline__ void gather_node(
    const int* __restrict__ rowp, const uint2* __restrict__ s_edge,
    const uint2* __restrict__ xv, const float4* __restrict__ coefLDS,
    unsigned short* __restrict__ uA, int node, int m, int lane) {
  const int eslot = lane >> 4, ch4 = lane & 15;
  const int beg = rowp[node], end = rowp[node + 1];
  float4 a0 = {0, 0, 0, 0}, a1 = {0, 0, 0, 0}, a2 = {0, 0, 0, 0}, a3 = {0, 0, 0, 0};
  int j = beg + eslot;
  uint2 rec0 = {0, 0}, rec1 = {0, 0}, xp = {0, 0};
  if (j < end) rec0 = s_edge[j];
  if (j + 4 < end) rec1 = s_edge[j + 4];
  if (j < end) xp = xv[(rec0.x & 0xFFFF) * 16 + ch4];
  while (j < end) {
    uint2 rec2 = {0, 0}, xp1 = {0, 0};
    if (j + 8 < end) rec2 = s_edge[j + 8];
    if (j + 4 < end) xp1 = xv[(rec1.x & 0xFFFF) * 16 + ch4];
    const float nm = __uint_as_float(rec0.y);
    const float4 c = coefLDS[rec0.x >> 16];
    const float w0 = nm * c.x, w1 = nm * c.y, w2 = nm * c.z, w3 = nm * c.w;
    const float x0 = bflo(xp.x), x1 = bfhi(xp.x), x2 = bflo(xp.y), x3 = bfhi(xp.y);
    a0.x += w0 * x0; a0.y += w0 * x1; a0.z += w0 * x2; a0.w += w0 * x3;
    a1.x += w1 * x0; a1.y += w1 * x1; a1.z += w1 * x2; a1.w += w1 * x3;
    a2.x += w2 * x0; a2.y += w2 * x1; a2.z += w2 * x2; a2.w += w2 * x3;
    a3.x += w3 * x0; a3.y += w3 * x1; a3.z += w3 * x2; a3.w += w3 * x3;
    j += 4; rec0 = rec1; rec1 = rec2; xp = xp1;
  }
#define RED1(x) x += __shfl_down(x, 32, 64); x += __shfl_down(x, 16, 64)
  RED1(a0.x); RED1(a0.y); RED1(a0.z); RED1(a0.w);
  RED1(a1.x); RED1(a1.y); RED1(a1.z); RED1(a1.w);
  RED1(a2.x); RED1(a2.y); RED1(a2.z); RED1(a2.w);
  RED1(a3.x); RED1(a3.y); RED1(a3.z); RED1(a3.w);
#undef RED1
  if (eslot == 0) {
    unsigned short* row = uA + m * ROWB + 4 * ch4;
    *(uint2*)(row + 0 * 64) = make_uint2(packbf2(a0.x, a0.y), packbf2(a0.z, a0.w));
    *(uint2*)(row + 1 * 64) = make_uint2(packbf2(a1.x, a1.y), packbf2(a1.z, a1.w));
    *(uint2*)(row + 2 * 64) = make_uint2(packbf2(a2.x, a2.y), packbf2(a2.z, a2.w));
    *(uint2*)(row + 3 * 64) = make_uint2(packbf2(a3.x, a3.y), packbf2(a3.z, a3.w));
  }
}

// ===========================================================================
// Fused layer 1 + Y2 pre-transform: 16 nodes/block, 4 waves.
//   gather -> uA[16][256] bf16
//   MFMA1 [16x256]@[256x64]: h1 = relu(uA@B1 + bias1)  (8 k-steps/wave)
//   MFMA2 [16x64]@[64x64]:   Y2[m][j=o*4+b] = h1 @ b2p  (2 k-steps/wave,
//     A read back from cmat fp32 -> packed bf16 in-register)
//   Y2 packed bf16 -> global [N][16] uint2 rows (row = o-major, b inner).
// ===========================================================================
__global__ __launch_bounds__(256) void k_l1_fused(
    const int* __restrict__ rowp, const uint2* __restrict__ s_edge,
    const uint2* __restrict__ xbf, const float* __restrict__ coef1,
    const unsigned short* __restrict__ b1T,  // [64][256] bf16
    const float* __restrict__ bias1,         // [64]
    const unsigned short* __restrict__ b2p,  // [64][64] bf16
    uint2* __restrict__ y2bf) {              // [N][16] uint2 = [N][64] bf16
  __shared__ __align__(16) unsigned short uA[16 * ROWB];  // 8.25 KB
  __shared__ float coefs[64];
  __shared__ float cmat[16 * 68];  // 4.25 KB
  const int wid = threadIdx.x >> 6, lane = threadIdx.x & 63;
  if (threadIdx.x < 64) coefs[threadIdx.x] = coef1[threadIdx.x];
  __syncthreads();
  const int nbase = blockIdx.x * 16;
#pragma unroll
  for (int jn = 0; jn < 4; ++jn) {
    const int m = wid * 4 + jn;
    gather_node(rowp, s_edge, xbf, (const float4*)coefs, uA, nbase + m, m, lane);
  }
  __syncthreads();
  // MFMA1: wave wid handles o-tile wid (o = 16*wid .. +15).
  const int nloc = lane & 15, kgrp = lane >> 4;
  f32x4 acc = {0.f, 0.f, 0.f, 0.f};
#pragma unroll
  for (int ks = 0; ks < 8; ++ks) {
    const int k0 = ks * 32 + kgrp * 8;
    const bf16x8 a = *(const bf16x8*)&uA[nloc * ROWB + k0];
    const bf16x8 b = *(const bf16x8*)&b1T[(wid * 16 + nloc) * 256 + k0];
    acc = __builtin_amdgcn_mfma_f32_16x16x32_bf16(a, b, acc, 0, 0, 0);
  }
  // h1 = relu(acc + bias) -> cmat[m][o]  (D: m=(lane>>4)*4+r, col=nloc)
  {
    const int o = wid * 16 + nloc;
    const float bs = bias1[o];
#pragma unroll
    for (int r = 0; r < 4; ++r) {
      const int m = (lane >> 4) * 4 + r;
      cmat[m * 68 + o] = fmaxf(acc[r] + bs, 0.f);
    }
  }
  __syncthreads();
  // MFMA2: Y2 = h1 @ b2p. Wave wid handles j-tile wid (j = 16*wid .. +15).
  f32x4 acc2 = {0.f, 0.f, 0.f, 0.f};
#pragma unroll
  for (int ks = 0; ks < 2; ++ks) {
    const int k0 = ks * 32 + kgrp * 8;
    const float4 c0 = *(const float4*)&cmat[nloc * 68 + k0];
    const float4 c1 = *(const float4*)&cmat[nloc * 68 + k0 + 4];
    union { bf16x8 v; unsigned u[4]; } au;
    au.u[0] = packbf2(c0.x, c0.y); au.u[1] = packbf2(c0.z, c0.w);
    au.u[2] = packbf2(c1.x, c1.y); au.u[3] = packbf2(c1.z, c1.w);
    const bf16x8 b = *(const bf16x8*)&b2p[(wid * 16 + nloc) * 64 + k0];
    acc2 = __builtin_amdgcn_mfma_f32_16x16x32_bf16(au.v, b, acc2, 0, 0, 0);
  }
  __syncthreads();  // all cmat reads done; reuse as Y2 staging
#pragma unroll
  for (int r = 0; r < 4; ++r) {
    const int m = (lane >> 4) * 4 + r;
    cmat[m * 68 + wid * 16 + nloc] = acc2[r];
  }
  __syncthreads();
  const int nl = threadIdx.x >> 4, c4 = threadIdx.x & 15;
  const float* cr = &cmat[nl * 68 + 4 * c4];
  y2bf[(size_t)(nbase + nl) * 16 + c4] =
      make_uint2(packbf2(cr[0], cr[1]), packbf2(cr[2], cr[3]));
}

// ===========================================================================
// Layer 2 (slim): out[d][o] = relu(bias2[o] +
//     sum_{e->d} nm_e * dot(coef2[t_e], Y2[src_e][o][:]))
// Wave = node; eslot = lane>>4 (4 edges), o = lane&15 (uint2 = 4 b values).
// Scalar accumulator; 2-ahead pipeline; shfl-reduce over eslots.
// ===========================================================================
__global__ __launch_bounds__(256) void k_l2_gather(
    const int* __restrict__ rowp, const uint2* __restrict__ s_edge,
    const uint2* __restrict__ y2bf, const float* __restrict__ coef2,
    const float* __restrict__ bias2, float* __restrict__ out) {
  __shared__ float coefs[64];
  if (threadIdx.x < 64) coefs[threadIdx.x] = coef2[threadIdx.x];
  __syncthreads();
  const float4* coefv = (const float4*)coefs;
  const int node = blockIdx.x * 4 + (threadIdx.x >> 6);
  const int lane = threadIdx.x & 63;
  const int eslot = lane >> 4, o = lane & 15;
  const int beg = rowp[node], end = rowp[node + 1];
  float acc = 0.f;
  int j = beg + eslot;
  uint2 rec0 = {0, 0}, rec1 = {0, 0}, yp = {0, 0};
  if (j < end) rec0 = s_edge[j];
  if (j + 4 < end) rec1 = s_edge[j + 4];
  if (j < end) yp = y2bf[(rec0.x & 0xFFFF) * 16 + o];
  while (j < end) {
    uint2 rec2 = {0, 0}, yp1 = {0, 0};
    if (j + 8 < end) rec2 = s_edge[j + 8];
    if (j + 4 < end) yp1 = y2bf[(rec1.x & 0xFFFF) * 16 + o];
    const float nm = __uint_as_float(rec0.y);
    const float4 c = coefv[rec0.x >> 16];
    acc += nm * (c.x * bflo(yp.x) + c.y * bfhi(yp.x) +
                 c.z * bflo(yp.y) + c.w * bfhi(yp.y));
    j += 4; rec0 = rec1; rec1 = rec2; yp = yp1;
  }
  acc += __shfl_down(acc, 32, 64);
  acc += __shfl_down(acc, 16, 64);
  if (eslot == 0) out[(size_t)node * 16 + o] = fmaxf(acc + bias2[o], 0.f);
}

extern "C" void kernel_launch(void* const* d_in, const int* in_sizes, int n_in,
                              void* d_out, int out_size, void* d_ws, size_t ws_size,
                              hipStream_t stream) {
  const float* feats  = (const float*)d_in[0];
  const int*   src    = (const int*)d_in[1];
  const int*   dst    = (const int*)d_in[2];
  const int*   etype  = (const int*)d_in[3];
  const float* enorm  = (const float*)d_in[4];
  const float* bases1 = (const float*)d_in[5];
  const float* coef1  = (const float*)d_in[6];
  const float* bias1  = (const float*)d_in[7];
  const float* bases2 = (const float*)d_in[8];
  const float* coef2  = (const float*)d_in[9];
  const float* bias2  = (const float*)d_in[10];

  // Workspace (~23 MB): xbf | y2bf | s_edge | rank | b1T | b2p | deg | rowp | bsum
  uint2* xbf    = (uint2*)d_ws;                       // N*16 uint2 (6.4 MB)
  uint2* y2bf   = xbf + (size_t)N_NODES * 16;         // N*16 uint2 (6.4 MB)
  uint2* s_edge = y2bf + (size_t)N_NODES * 16;        // E uint2 (6.4 MB)
  int*   rank   = (int*)(s_edge + N_EDGES);           // E ints (3.2 MB)
  unsigned short* b1T = (unsigned short*)(rank + N_EDGES);  // 16384 (32 KB)
  unsigned short* b2p = b1T + 64 * 256;               // 4096 (8 KB)
  int*   deg    = (int*)(b2p + 64 * 64);              // N
  int*   rowp   = deg + N_NODES;                      // N+1
  int*   bsum   = rowp + N_NODES + 1;                 // 64

  const int SCAN_BLKS = (N_NODES + 1023) / 1024;  // 49

  hipMemsetAsync(deg, 0, N_NODES * sizeof(int), stream);

  k_prep_hist<<<3126, 256, 0, stream>>>((const float4*)feats, xbf, bases1,
                                        bases2, b1T, b2p, dst, deg, rank);
  k_scan1<<<SCAN_BLKS, 1024, 0, stream>>>(deg, rowp, bsum);
  k_scan3<<<SCAN_BLKS, 1024, 0, stream>>>(rowp, bsum, SCAN_BLKS);
  k_scatter<<<N_EDGES / 256, 256, 0, stream>>>(src, dst, etype, enorm,
                                               rowp, rank, s_edge);
  k_l1_fused<<<N_NODES / 16, 256, 0, stream>>>(rowp, s_edge, xbf, coef1,
                                               b1T, bias1, b2p, y2bf);
  k_l2_gather<<<N_NODES / 4, 256, 0, stream>>>(rowp, s_edge, y2bf, coef2,
                                               bias2, (float*)d_out);
}